// Round 1
// baseline (1114.564 us; speedup 1.0000x reference)
//
#include <hip/hip_runtime.h>

#define NN 50000
#define NE 800000

__device__ __forceinline__ float silu_f(float x) { return x / (1.0f + __expf(-x)); }

// ---------------------------------------------------------------------------
// K1: x_s = s @ W1_s ; x_v planar: x_v[n*96 + c*32 + o] = sum_u v[n][u][c]*W1_v[u][o]
// ---------------------------------------------------------------------------
__global__ __launch_bounds__(256) void k_node_transform(
    const float* __restrict__ node_feats,
    const float* __restrict__ W1_s,
    const float* __restrict__ W1_v,
    float* __restrict__ x_s,
    float* __restrict__ x_v)
{
    __shared__ float sW1s[32 * 32];
    __shared__ float sW1v[32 * 32];
    __shared__ float sfeat[8][128];
    int t = threadIdx.x;
    for (int i = t; i < 1024; i += 256) { sW1s[i] = W1_s[i]; sW1v[i] = W1_v[i]; }
    int nodeBase = blockIdx.x * 8;
    for (int i = t; i < 8 * 128; i += 256) {
        int nn = nodeBase + (i >> 7);
        sfeat[i >> 7][i & 127] = (nn < NN) ? node_feats[(long)nn * 128 + (i & 127)] : 0.0f;
    }
    __syncthreads();
    int g = t >> 5, o = t & 31;
    int n = nodeBase + g;
    if (n >= NN) return;
    float accs = 0.f, acc0 = 0.f, acc1 = 0.f, acc2 = 0.f;
#pragma unroll
    for (int u = 0; u < 32; ++u) {
        float su  = sfeat[g][u];
        float vu0 = sfeat[g][32 + u * 3 + 0];
        float vu1 = sfeat[g][32 + u * 3 + 1];
        float vu2 = sfeat[g][32 + u * 3 + 2];
        float ws = sW1s[u * 32 + o];
        float wv = sW1v[u * 32 + o];
        accs += su * ws;
        acc0 += vu0 * wv;
        acc1 += vu1 * wv;
        acc2 += vu2 * wv;
    }
    x_s[(long)n * 32 + o] = accs;
    x_v[(long)n * 96 +      o] = acc0;
    x_v[(long)n * 96 + 32 + o] = acc1;
    x_v[(long)n * 96 + 64 + o] = acc2;
}

// ---------------------------------------------------------------------------
// CSR build: histogram -> single-block scan -> fill
// ---------------------------------------------------------------------------
__global__ __launch_bounds__(256) void k_hist(const int* __restrict__ edge_dst,
                                              int* __restrict__ counts)
{
    int e = blockIdx.x * 256 + threadIdx.x;
    if (e < NE) atomicAdd(&counts[edge_dst[e]], 1);
}

__global__ __launch_bounds__(1024) void k_scan(const int* __restrict__ counts,
                                               int* __restrict__ row_ptr,
                                               int* __restrict__ cursor)
{
    __shared__ int wsum[16];
    __shared__ int carry_s;
    int t = threadIdx.x;
    int lane = t & 63, w = t >> 6;
    if (t == 0) carry_s = 0;
    __syncthreads();
    for (int base = 0; base < NN; base += 1024) {
        int i = base + t;
        int v = (i < NN) ? counts[i] : 0;
        int s = v;
#pragma unroll
        for (int d = 1; d < 64; d <<= 1) {
            int o = __shfl_up(s, d, 64);
            if (lane >= d) s += o;
        }
        if (lane == 63) wsum[w] = s;
        __syncthreads();
        if (w == 0) {
            int ws = (lane < 16) ? wsum[lane] : 0;
#pragma unroll
            for (int d = 1; d < 16; d <<= 1) {
                int o = __shfl_up(ws, d, 64);
                if (lane >= d) ws += o;
            }
            if (lane < 16) wsum[lane] = ws;
        }
        __syncthreads();
        int excl = (s - v) + ((w > 0) ? wsum[w - 1] : 0) + carry_s;
        if (i < NN) { row_ptr[i] = excl; cursor[i] = excl; }
        int total = wsum[15];
        __syncthreads();
        if (t == 0) carry_s += total;
        __syncthreads();
    }
    if (t == 0) row_ptr[NN] = carry_s;
}

__global__ __launch_bounds__(256) void k_fill(const int* __restrict__ edge_dst,
                                              int* __restrict__ cursor,
                                              int* __restrict__ edge_ids)
{
    int e = blockIdx.x * 256 + threadIdx.x;
    if (e < NE) {
        int slot = atomicAdd(&cursor[edge_dst[e]], 1);
        edge_ids[slot] = e;
    }
}

// ---------------------------------------------------------------------------
// Prep: tile/transpose fc_w2 [64][160] -> w2t[jb][p][lane][r] (jb<16, p<5,
// lane<32, r<4) so the k_gather inner loop reads 512B fully-coalesced float4s:
//   w2t[((jb*5+p)*32+lane)*4 + r] = fc_w2[(jb*4+r)*160 + p*32+lane]
// ---------------------------------------------------------------------------
__global__ __launch_bounds__(256) void k_w2t(const float* __restrict__ fc_w2,
                                             float* __restrict__ w2t)
{
    int i = blockIdx.x * 256 + threadIdx.x;
    if (i < 64 * 160) {
        int r    = i & 3;
        int rest = i >> 2;          // (jb*5+p)*32 + lane
        int lane = rest & 31;
        int pp   = rest >> 5;       // jb*5 + p
        int jb   = pp / 5;
        int p    = pp - jb * 5;
        w2t[i] = fc_w2[(jb * 4 + r) * 160 + p * 32 + lane];
    }
}

// ---------------------------------------------------------------------------
// K2: fused gather: per dst node, loop CSR edge list; edge MLP + messages
// accumulated in registers (NO atomics), then fused K3 epilogue.
// block = 256 = 8 groups x 32 lanes, group = one node. 4-edge inner blocking.
// fc_w2 is NOT staged in LDS (was 40KB -> occupancy cap of 2 blocks/CU);
// it is read from global (L1/L2-resident 40KB, coalesced float4 broadcast).
// LDS now ~21.3KB -> 4 blocks/CU (VGPR-capped), 2x occupancy.
// ---------------------------------------------------------------------------
__global__ __launch_bounds__(256, 4) void k_gather(
    const float* __restrict__ edge_embedding,
    const float* __restrict__ edge_attrs,
    const int*   __restrict__ edge_src,
    const float* __restrict__ fc_w1,
    const float* __restrict__ fc_b1,
    const float* __restrict__ w2t,
    const float* __restrict__ x_s,
    const float* __restrict__ x_v,
    const int*   __restrict__ row_ptr,
    const int*   __restrict__ edge_ids,
    const float* __restrict__ node_feats,
    const float* __restrict__ node_attrs,
    const float* __restrict__ W2_s,
    const float* __restrict__ W2_v,
    const float* __restrict__ Wsc_s,
    const float* __restrict__ Wsc_v,
    float* __restrict__ out)
{
    __shared__ __align__(16) float sw1[8 * 64];     // 2 KB
    __shared__ float sb1[64];
    __shared__ __align__(16) float hbuf[8][256];    // 8 KB  (4 edges x 64 hidden) / reused for feats+attrs
    __shared__ float asbuf[8][64];                  // 2 KB
    __shared__ float avbuf[8][288];                 // 9 KB

    int t = threadIdx.x;
    for (int i = t; i < 8 * 64; i += 256) sw1[i] = fc_w1[i];
    if (t < 64) sb1[t] = fc_b1[t];
    __syncthreads();

    int g = t >> 5, lane = t & 31;
    int n = blockIdx.x * 8 + g;
    if (n >= NN) return;

    int start = row_ptr[n];
    int end   = row_ptr[n + 1];

    float as0 = 0.f, as1 = 0.f;
    float av[9];
#pragma unroll
    for (int p = 0; p < 9; ++p) av[p] = 0.f;

    float* hb = &hbuf[g][0];
    const float4* w2t4 = (const float4*)w2t;   // float4 index = (jb*5+p)*32 + lane
    const float INV_SQRT3 = 0.5773502691896258f;
    const float INV_SQRT2 = 0.7071067811865476f;
    const float INV_NEI   = 0.25f;

    for (int i = start; i < end; i += 4) {
        int ne = end - i;          // >= 1
        int eid[4];
#pragma unroll
        for (int k = 0; k < 4; ++k) eid[k] = edge_ids[(k < ne) ? (i + k) : i];

        // ---- hidden layer for 4 edges (dummies duplicate edge 0: safe values)
        float em[4][8];
#pragma unroll
        for (int k = 0; k < 4; ++k) {
            *(float4*)&em[k][0] = *(const float4*)&edge_embedding[(long)eid[k] * 8];
            *(float4*)&em[k][4] = *(const float4*)&edge_embedding[(long)eid[k] * 8 + 4];
        }
#pragma unroll
        for (int k = 0; k < 4; ++k) {
            float h0 = sb1[lane], h1 = sb1[lane + 32];
#pragma unroll
            for (int q = 0; q < 8; ++q) {
                float e = em[k][q];
                h0 += e * sw1[q * 64 + lane];
                h1 += e * sw1[q * 64 + lane + 32];
            }
            hb[k * 64 + lane]      = silu_f(h0);
            hb[k * 64 + 32 + lane] = silu_f(h1);
        }
        // same-wave LDS RAW: in-order DS pipe + compiler waitcnt; no barrier
        // (barrier here would be illegal: divergent trip counts across groups)

        // ---- w = h @ fc_w2 : 5 path columns per lane, 4-edge register block
        // w from GLOBAL (w2t, coalesced 512B float4, L1/L2-hit); h from LDS
        // via broadcast float4 (uniform address -> conflict-free).
        float acc[5][4];
#pragma unroll
        for (int p = 0; p < 5; ++p)
#pragma unroll
            for (int k = 0; k < 4; ++k) acc[p][k] = 0.f;

#pragma unroll 2
        for (int jb = 0; jb < 16; ++jb) {
            const float4* wr = w2t4 + jb * 160 + lane;
            float4 w0 = wr[0];
            float4 w1 = wr[32];
            float4 w2 = wr[64];
            float4 w3 = wr[96];
            float4 w4 = wr[128];
#pragma unroll
            for (int k = 0; k < 4; ++k) {
                float4 h4 = *(const float4*)&hb[k * 64 + jb * 4];
                acc[0][k] += h4.x * w0.x + h4.y * w0.y + h4.z * w0.z + h4.w * w0.w;
                acc[1][k] += h4.x * w1.x + h4.y * w1.y + h4.z * w1.z + h4.w * w1.w;
                acc[2][k] += h4.x * w2.x + h4.y * w2.y + h4.z * w2.z + h4.w * w2.w;
                acc[3][k] += h4.x * w3.x + h4.y * w3.y + h4.z * w3.z + h4.w * w3.w;
                acc[4][k] += h4.x * w4.x + h4.y * w4.y + h4.z * w4.z + h4.w * w4.w;
            }
        }

        // ---- messages, register accumulate
#pragma unroll
        for (int k = 0; k < 4; ++k) {
            if (k >= ne) break;
            int e = eid[k];
            int src = edge_src[e];
            float4 at = *(const float4*)&edge_attrs[(long)e * 4];
            float xs  = x_s[(long)src * 32 + lane];
            float xv0 = x_v[(long)src * 96 +      lane];
            float xv1 = x_v[(long)src * 96 + 32 + lane];
            float xv2 = x_v[(long)src * 96 + 64 + lane];
            float w00 = acc[0][k], w01 = acc[1][k], w10 = acc[2][k];
            float w11s = acc[3][k], w11v = acc[4][k];

            as0 += w00 * xs * at.x;
            float dot = xv0 * at.y + xv1 * at.z + xv2 * at.w;
            as1 += w11s * dot * INV_SQRT3;
            float t01 = w01 * xs;
            av[0] += t01 * at.y; av[1] += t01 * at.z; av[2] += t01 * at.w;
            float t10 = w10 * at.x;
            av[3] += t10 * xv0; av[4] += t10 * xv1; av[5] += t10 * xv2;
            float k2 = w11v * INV_SQRT2;
            av[6] += k2 * (xv1 * at.w - xv2 * at.z);
            av[7] += k2 * (xv2 * at.y - xv0 * at.w);
            av[8] += k2 * (xv0 * at.z - xv1 * at.y);
        }
    }

    // ---- stage accumulators (group-private LDS, same-wave only)
    asbuf[g][lane]      = as0 * INV_NEI;
    asbuf[g][32 + lane] = as1 * INV_NEI;
#pragma unroll
    for (int p = 0; p < 3; ++p)
#pragma unroll
        for (int c = 0; c < 3; ++c)
            avbuf[g][(p * 32 + lane) * 3 + c] = av[p * 3 + c] * INV_NEI;

    // ---- stage this node's feats + attrs into hbuf (reuse)
    *(float4*)&hb[lane * 4] = *(const float4*)&node_feats[(long)n * 128 + lane * 4];
    if (lane < 16) hb[128 + lane] = node_attrs[(long)n * 16 + lane];

    // ---- fused epilogue (K3): W2 GEMVs + Wsc bilinear (t-form) + gate + residual
    int o = lane;
    float ys0 = 0.f, ys1 = 0.f, yv0 = 0.f, yv1 = 0.f, yv2 = 0.f;

#pragma unroll 8
    for (int u = 0; u < 64; ++u) {
        float as = asbuf[g][u];
        ys0 += as * W2_s[u * 64 + o];
        ys1 += as * W2_s[u * 64 + 32 + o];
    }
#pragma unroll 8
    for (int u = 0; u < 96; ++u) {
        float wv = W2_v[u * 32 + o];
        yv0 += avbuf[g][u * 3 + 0] * wv;
        yv1 += avbuf[g][u * 3 + 1] * wv;
        yv2 += avbuf[g][u * 3 + 2] * wv;
    }

    float att[16];
#pragma unroll
    for (int a = 0; a < 16; ++a) att[a] = hb[128 + a];

    for (int u = 0; u < 32; ++u) {
        const float* Wsp = &Wsc_s[u * 1024 + o];
        const float* Wvp = &Wsc_v[u * 512 + o];
        float t0 = 0.f, t1 = 0.f, tv = 0.f;
#pragma unroll
        for (int a = 0; a < 16; ++a) {
            float aa = att[a];
            t0 += aa * Wsp[a * 64];
            t1 += aa * Wsp[a * 64 + 32];
            tv += aa * Wvp[a * 32];
        }
        float su = hb[u];
        ys0 += su * t0;
        ys1 += su * t1;
        float vv0 = hb[32 + u * 3 + 0];
        float vv1 = hb[32 + u * 3 + 1];
        float vv2 = hb[32 + u * 3 + 2];
        yv0 += vv0 * tv;
        yv1 += vv1 * tv;
        yv2 += vv2 * tv;
    }

    float os   = silu_f(ys0);
    float gate = silu_f(ys1);
    long base = (long)n * 128;
    out[base + o] = hb[o] + os;
    out[base + 32 + o * 3 + 0] = hb[32 + o * 3 + 0] + yv0 * gate;
    out[base + 32 + o * 3 + 1] = hb[32 + o * 3 + 1] + yv1 * gate;
    out[base + 32 + o * 3 + 2] = hb[32 + o * 3 + 2] + yv2 * gate;
}

// ---------------------------------------------------------------------------
extern "C" void kernel_launch(void* const* d_in, const int* in_sizes, int n_in,
                              void* d_out, int out_size, void* d_ws, size_t ws_size,
                              hipStream_t stream) {
    const float* node_feats     = (const float*)d_in[0];
    const float* node_attrs     = (const float*)d_in[1];
    const float* edge_embedding = (const float*)d_in[2];
    const float* edge_attrs     = (const float*)d_in[3];
    const int*   edge_src       = (const int*)d_in[4];
    const int*   edge_dst       = (const int*)d_in[5];
    const float* W1_s  = (const float*)d_in[6];
    const float* W1_v  = (const float*)d_in[7];
    const float* fc_w1 = (const float*)d_in[8];
    const float* fc_b1 = (const float*)d_in[9];
    const float* fc_w2 = (const float*)d_in[10];
    const float* W2_s  = (const float*)d_in[11];
    const float* W2_v  = (const float*)d_in[12];
    const float* Wsc_s = (const float*)d_in[13];
    const float* Wsc_v = (const float*)d_in[14];
    float* out = (float*)d_out;

    float* ws  = (float*)d_ws;
    float* x_s = ws;                       // NN*32 floats
    float* x_v = ws + (long)NN * 32;       // NN*96 floats (planar)
    int* ibase    = (int*)(ws + (long)NN * 128);
    int* counts   = ibase;                 // NN
    int* row_ptr  = ibase + NN;            // NN+1
    int* cursor   = ibase + 2 * NN + 1;    // NN
    int* edge_ids = ibase + 3 * NN + 1;    // NE
    // 16B-aligned tail: (3*NN+4+NE) ints from a 16B-aligned base
    float* w2t    = (float*)(ibase + 3 * NN + 4 + NE);  // 64*160 floats (40KB)

    hipMemsetAsync(counts, 0, (size_t)NN * sizeof(int), stream);
    k_w2t<<<40, 256, 0, stream>>>(fc_w2, w2t);
    k_hist<<<(NE + 255) / 256, 256, 0, stream>>>(edge_dst, counts);
    k_node_transform<<<(NN + 7) / 8, 256, 0, stream>>>(node_feats, W1_s, W1_v, x_s, x_v);
    k_scan<<<1, 1024, 0, stream>>>(counts, row_ptr, cursor);
    k_fill<<<(NE + 255) / 256, 256, 0, stream>>>(edge_dst, cursor, edge_ids);
    k_gather<<<(NN + 7) / 8, 256, 0, stream>>>(edge_embedding, edge_attrs, edge_src,
                                               fc_w1, fc_b1, w2t, x_s, x_v,
                                               row_ptr, edge_ids,
                                               node_feats, node_attrs,
                                               W2_s, W2_v, Wsc_s, Wsc_v, out);
}

// Round 2
// 1108.675 us; speedup vs baseline: 1.0053x; 1.0053x over previous
//
#include <hip/hip_runtime.h>

#define NN 50000
#define NE 800000

__device__ __forceinline__ float silu_f(float x) { return x / (1.0f + __expf(-x)); }

// ---------------------------------------------------------------------------
// K1: x_s = s @ W1_s ; x_v planar: x_v[n*96 + c*32 + o] = sum_u v[n][u][c]*W1_v[u][o]
// ---------------------------------------------------------------------------
__global__ __launch_bounds__(256) void k_node_transform(
    const float* __restrict__ node_feats,
    const float* __restrict__ W1_s,
    const float* __restrict__ W1_v,
    float* __restrict__ x_s,
    float* __restrict__ x_v)
{
    __shared__ float sW1s[32 * 32];
    __shared__ float sW1v[32 * 32];
    __shared__ float sfeat[8][128];
    int t = threadIdx.x;
    for (int i = t; i < 1024; i += 256) { sW1s[i] = W1_s[i]; sW1v[i] = W1_v[i]; }
    int nodeBase = blockIdx.x * 8;
    for (int i = t; i < 8 * 128; i += 256) {
        int nn = nodeBase + (i >> 7);
        sfeat[i >> 7][i & 127] = (nn < NN) ? node_feats[(long)nn * 128 + (i & 127)] : 0.0f;
    }
    __syncthreads();
    int g = t >> 5, o = t & 31;
    int n = nodeBase + g;
    if (n >= NN) return;
    float accs = 0.f, acc0 = 0.f, acc1 = 0.f, acc2 = 0.f;
#pragma unroll
    for (int u = 0; u < 32; ++u) {
        float su  = sfeat[g][u];
        float vu0 = sfeat[g][32 + u * 3 + 0];
        float vu1 = sfeat[g][32 + u * 3 + 1];
        float vu2 = sfeat[g][32 + u * 3 + 2];
        float ws = sW1s[u * 32 + o];
        float wv = sW1v[u * 32 + o];
        accs += su * ws;
        acc0 += vu0 * wv;
        acc1 += vu1 * wv;
        acc2 += vu2 * wv;
    }
    x_s[(long)n * 32 + o] = accs;
    x_v[(long)n * 96 +      o] = acc0;
    x_v[(long)n * 96 + 32 + o] = acc1;
    x_v[(long)n * 96 + 64 + o] = acc2;
}

// ---------------------------------------------------------------------------
// CSR build: histogram -> single-block scan -> fill
// ---------------------------------------------------------------------------
__global__ __launch_bounds__(256) void k_hist(const int* __restrict__ edge_dst,
                                              int* __restrict__ counts)
{
    int e = blockIdx.x * 256 + threadIdx.x;
    if (e < NE) atomicAdd(&counts[edge_dst[e]], 1);
}

__global__ __launch_bounds__(1024) void k_scan(const int* __restrict__ counts,
                                               int* __restrict__ row_ptr,
                                               int* __restrict__ cursor)
{
    __shared__ int wsum[16];
    __shared__ int carry_s;
    int t = threadIdx.x;
    int lane = t & 63, w = t >> 6;
    if (t == 0) carry_s = 0;
    __syncthreads();
    for (int base = 0; base < NN; base += 1024) {
        int i = base + t;
        int v = (i < NN) ? counts[i] : 0;
        int s = v;
#pragma unroll
        for (int d = 1; d < 64; d <<= 1) {
            int o = __shfl_up(s, d, 64);
            if (lane >= d) s += o;
        }
        if (lane == 63) wsum[w] = s;
        __syncthreads();
        if (w == 0) {
            int ws = (lane < 16) ? wsum[lane] : 0;
#pragma unroll
            for (int d = 1; d < 16; d <<= 1) {
                int o = __shfl_up(ws, d, 64);
                if (lane >= d) ws += o;
            }
            if (lane < 16) wsum[lane] = ws;
        }
        __syncthreads();
        int excl = (s - v) + ((w > 0) ? wsum[w - 1] : 0) + carry_s;
        if (i < NN) { row_ptr[i] = excl; cursor[i] = excl; }
        int total = wsum[15];
        __syncthreads();
        if (t == 0) carry_s += total;
        __syncthreads();
    }
    if (t == 0) row_ptr[NN] = carry_s;
}

__global__ __launch_bounds__(256) void k_fill(const int* __restrict__ edge_dst,
                                              int* __restrict__ cursor,
                                              int* __restrict__ edge_ids)
{
    int e = blockIdx.x * 256 + threadIdx.x;
    if (e < NE) {
        int slot = atomicAdd(&cursor[edge_dst[e]], 1);
        edge_ids[slot] = e;
    }
}

// ---------------------------------------------------------------------------
// w2t: plain transpose w2t[c*64+j] = fc_w2[j*160+c]  (for k_edge_mlp's
// contiguous, wave-uniform weight columns)
// ---------------------------------------------------------------------------
__global__ __launch_bounds__(256) void k_w2t(const float* __restrict__ fc_w2,
                                             float* __restrict__ w2t)
{
    int i = blockIdx.x * 256 + threadIdx.x;
    if (i < 10240) {
        int c = i >> 6, j = i & 63;
        w2t[i] = fc_w2[j * 160 + c];
    }
}

// ---------------------------------------------------------------------------
// k_edge_mlp: edge-major MLP, ONE EDGE PER THREAD, processed in CSR-slot
// order so k_gather later streams w sequentially.
//   h[64] lives in registers; weight reads are wave-uniform (scalar/broadcast,
//   amortized over 64 edges/wave instead of 4).  Output transposed through
//   LDS in 32-col chunks so global stores are coalesced.
// NE = 3125 * 256 exactly -> no tail guard needed.
// ---------------------------------------------------------------------------
__global__ __launch_bounds__(256) void k_edge_mlp(
    const float* __restrict__ edge_embedding,
    const int*   __restrict__ edge_ids,
    const float* __restrict__ fc_w1,
    const float* __restrict__ fc_b1,
    const float* __restrict__ w2t,
    float* __restrict__ wbuf)
{
    __shared__ float sch[256][33];   // 33 KB, +1 pad col
    int t = threadIdx.x;
    long sid = (long)blockIdx.x * 256 + t;
    int e = edge_ids[sid];
    float em[8];
    *(float4*)&em[0] = *(const float4*)&edge_embedding[(long)e * 8];
    *(float4*)&em[4] = *(const float4*)&edge_embedding[(long)e * 8 + 4];

    float h[64];
#pragma unroll
    for (int j = 0; j < 64; ++j) {
        float a = fc_b1[j];
#pragma unroll
        for (int q = 0; q < 8; ++q) a += em[q] * fc_w1[q * 64 + j];
        h[j] = silu_f(a);
    }

    long blockBase = (long)blockIdx.x * 256 * 160;
#pragma unroll 1
    for (int cc = 0; cc < 160; cc += 32) {
#pragma unroll 2
        for (int c0 = 0; c0 < 32; c0 += 4) {
            float a0 = 0.f, a1 = 0.f, a2 = 0.f, a3 = 0.f;
            const float* wp = &w2t[(cc + c0) * 64];   // wave-uniform address
#pragma unroll
            for (int j = 0; j < 64; ++j) {
                float hj = h[j];
                a0 += hj * wp[j];
                a1 += hj * wp[64 + j];
                a2 += hj * wp[128 + j];
                a3 += hj * wp[192 + j];
            }
            sch[t][c0 + 0] = a0; sch[t][c0 + 1] = a1;
            sch[t][c0 + 2] = a2; sch[t][c0 + 3] = a3;
        }
        __syncthreads();
        for (int k = t; k < 256 * 32; k += 256) {
            int row = k >> 5, col = k & 31;
            wbuf[blockBase + (long)row * 160 + cc + col] = sch[row][col];
        }
        __syncthreads();
    }
}

// ---------------------------------------------------------------------------
// k_gather (NEW): per dst node, stream precomputed w (slot-sequential),
// gather x, accumulate messages in registers, fused epilogue.
// block = 256 = 8 groups x 32 lanes, group = one node. No block-wide barriers.
// ---------------------------------------------------------------------------
__global__ __launch_bounds__(256) void k_gather(
    const float* __restrict__ edge_attrs,
    const int*   __restrict__ edge_src,
    const float* __restrict__ wbuf,
    const float* __restrict__ x_s,
    const float* __restrict__ x_v,
    const int*   __restrict__ row_ptr,
    const int*   __restrict__ edge_ids,
    const float* __restrict__ node_feats,
    const float* __restrict__ node_attrs,
    const float* __restrict__ W2_s,
    const float* __restrict__ W2_v,
    const float* __restrict__ Wsc_s,
    const float* __restrict__ Wsc_v,
    float* __restrict__ out)
{
    __shared__ __align__(16) float sfeat[8][144];   // feats(128)+attrs(16), group-private
    __shared__ float asbuf[8][64];
    __shared__ float avbuf[8][288];

    int t = threadIdx.x;
    int g = t >> 5, lane = t & 31;
    int n = blockIdx.x * 8 + g;
    if (n >= NN) return;

    int start = row_ptr[n];
    int end   = row_ptr[n + 1];

    float as0 = 0.f, as1 = 0.f;
    float av[9];
#pragma unroll
    for (int p = 0; p < 9; ++p) av[p] = 0.f;

    const float INV_SQRT3 = 0.5773502691896258f;
    const float INV_SQRT2 = 0.7071067811865476f;
    const float INV_NEI   = 0.25f;

    for (int i = start; i < end; i += 4) {
        int ne = end - i;
        int sl[4], eid[4], src[4];
#pragma unroll
        for (int k = 0; k < 4; ++k) sl[k] = (k < ne) ? (i + k) : i;
#pragma unroll
        for (int k = 0; k < 4; ++k) eid[k] = edge_ids[sl[k]];
#pragma unroll
        for (int k = 0; k < 4; ++k) src[k] = edge_src[eid[k]];
        float4 at[4];
#pragma unroll
        for (int k = 0; k < 4; ++k) at[k] = *(const float4*)&edge_attrs[(long)eid[k] * 4];
        float w00[4], w01[4], w10[4], w11s[4], w11v[4];
#pragma unroll
        for (int k = 0; k < 4; ++k) {
            const float* wp = &wbuf[(long)sl[k] * 160 + lane];
            w00[k] = wp[0]; w01[k] = wp[32]; w10[k] = wp[64];
            w11s[k] = wp[96]; w11v[k] = wp[128];
        }
        float xs[4], xv0[4], xv1[4], xv2[4];
#pragma unroll
        for (int k = 0; k < 4; ++k) {
            xs[k]  = x_s[(long)src[k] * 32 + lane];
            xv0[k] = x_v[(long)src[k] * 96 +      lane];
            xv1[k] = x_v[(long)src[k] * 96 + 32 + lane];
            xv2[k] = x_v[(long)src[k] * 96 + 64 + lane];
        }
#pragma unroll
        for (int k = 0; k < 4; ++k) {
            if (k >= ne) break;
            float4 a4 = at[k];
            as0 += w00[k] * xs[k] * a4.x;
            float dot = xv0[k] * a4.y + xv1[k] * a4.z + xv2[k] * a4.w;
            as1 += w11s[k] * dot * INV_SQRT3;
            float t01 = w01[k] * xs[k];
            av[0] += t01 * a4.y; av[1] += t01 * a4.z; av[2] += t01 * a4.w;
            float t10 = w10[k] * a4.x;
            av[3] += t10 * xv0[k]; av[4] += t10 * xv1[k]; av[5] += t10 * xv2[k];
            float k2 = w11v[k] * INV_SQRT2;
            av[6] += k2 * (xv1[k] * a4.w - xv2[k] * a4.z);
            av[7] += k2 * (xv2[k] * a4.y - xv0[k] * a4.w);
            av[8] += k2 * (xv0[k] * a4.z - xv1[k] * a4.y);
        }
    }

    // ---- stage accumulators (group-private LDS, same-wave only)
    asbuf[g][lane]      = as0 * INV_NEI;
    asbuf[g][32 + lane] = as1 * INV_NEI;
#pragma unroll
    for (int p = 0; p < 3; ++p)
#pragma unroll
        for (int c = 0; c < 3; ++c)
            avbuf[g][(p * 32 + lane) * 3 + c] = av[p * 3 + c] * INV_NEI;

    // ---- stage this node's feats + attrs (same-wave RAW, no barrier needed)
    float* fb = &sfeat[g][0];
    *(float4*)&fb[lane * 4] = *(const float4*)&node_feats[(long)n * 128 + lane * 4];
    if (lane < 16) fb[128 + lane] = node_attrs[(long)n * 16 + lane];

    // ---- fused epilogue: W2 GEMVs + Wsc bilinear (t-form) + gate + residual
    int o = lane;
    float ys0 = 0.f, ys1 = 0.f, yv0 = 0.f, yv1 = 0.f, yv2 = 0.f;

#pragma unroll 8
    for (int u = 0; u < 64; ++u) {
        float as = asbuf[g][u];
        ys0 += as * W2_s[u * 64 + o];
        ys1 += as * W2_s[u * 64 + 32 + o];
    }
#pragma unroll 8
    for (int u = 0; u < 96; ++u) {
        float wv = W2_v[u * 32 + o];
        yv0 += avbuf[g][u * 3 + 0] * wv;
        yv1 += avbuf[g][u * 3 + 1] * wv;
        yv2 += avbuf[g][u * 3 + 2] * wv;
    }

    float att[16];
#pragma unroll
    for (int a = 0; a < 16; ++a) att[a] = fb[128 + a];

    for (int u = 0; u < 32; ++u) {
        const float* Wsp = &Wsc_s[u * 1024 + o];
        const float* Wvp = &Wsc_v[u * 512 + o];
        float t0 = 0.f, t1 = 0.f, tv = 0.f;
#pragma unroll
        for (int a = 0; a < 16; ++a) {
            float aa = att[a];
            t0 += aa * Wsp[a * 64];
            t1 += aa * Wsp[a * 64 + 32];
            tv += aa * Wvp[a * 32];
        }
        float su = fb[u];
        ys0 += su * t0;
        ys1 += su * t1;
        float vv0 = fb[32 + u * 3 + 0];
        float vv1 = fb[32 + u * 3 + 1];
        float vv2 = fb[32 + u * 3 + 2];
        yv0 += vv0 * tv;
        yv1 += vv1 * tv;
        yv2 += vv2 * tv;
    }

    float os   = silu_f(ys0);
    float gate = silu_f(ys1);
    long base = (long)n * 128;
    out[base + o] = fb[o] + os;
    out[base + 32 + o * 3 + 0] = fb[32 + o * 3 + 0] + yv0 * gate;
    out[base + 32 + o * 3 + 1] = fb[32 + o * 3 + 1] + yv1 * gate;
    out[base + 32 + o * 3 + 2] = fb[32 + o * 3 + 2] + yv2 * gate;
}

// ---------------------------------------------------------------------------
// FALLBACK (only if ws_size can't hold the 512MB w buffer): Round-0 fused
// kernel (known-good, 88 VGPR, no spill).
// ---------------------------------------------------------------------------
__global__ __launch_bounds__(256) void k_gather_fused(
    const float* __restrict__ edge_embedding,
    const float* __restrict__ edge_attrs,
    const int*   __restrict__ edge_src,
    const float* __restrict__ fc_w1,
    const float* __restrict__ fc_b1,
    const float* __restrict__ fc_w2,
    const float* __restrict__ x_s,
    const float* __restrict__ x_v,
    const int*   __restrict__ row_ptr,
    const int*   __restrict__ edge_ids,
    const float* __restrict__ node_feats,
    const float* __restrict__ node_attrs,
    const float* __restrict__ W2_s,
    const float* __restrict__ W2_v,
    const float* __restrict__ Wsc_s,
    const float* __restrict__ Wsc_v,
    float* __restrict__ out)
{
    __shared__ __align__(16) float sw1[8 * 64];
    __shared__ float sb1[64];
    __shared__ __align__(16) float sw2[64 * 160];
    __shared__ __align__(16) float hbuf[8][256];
    __shared__ float asbuf[8][64];
    __shared__ float avbuf[8][288];

    int t = threadIdx.x;
    for (int i = t; i < 8 * 64; i += 256) sw1[i] = fc_w1[i];
    if (t < 64) sb1[t] = fc_b1[t];
    for (int i = t; i < 64 * 160; i += 256) sw2[i] = fc_w2[i];
    __syncthreads();

    int g = t >> 5, lane = t & 31;
    int n = blockIdx.x * 8 + g;
    if (n >= NN) return;

    int start = row_ptr[n];
    int end   = row_ptr[n + 1];

    float as0 = 0.f, as1 = 0.f;
    float av[9];
#pragma unroll
    for (int p = 0; p < 9; ++p) av[p] = 0.f;

    float* hb = &hbuf[g][0];
    const float INV_SQRT3 = 0.5773502691896258f;
    const float INV_SQRT2 = 0.7071067811865476f;
    const float INV_NEI   = 0.25f;

    for (int i = start; i < end; i += 4) {
        int ne = end - i;
        int eid[4];
#pragma unroll
        for (int k = 0; k < 4; ++k) eid[k] = edge_ids[(k < ne) ? (i + k) : i];
        float em[4][8];
#pragma unroll
        for (int k = 0; k < 4; ++k) {
            *(float4*)&em[k][0] = *(const float4*)&edge_embedding[(long)eid[k] * 8];
            *(float4*)&em[k][4] = *(const float4*)&edge_embedding[(long)eid[k] * 8 + 4];
        }
#pragma unroll
        for (int k = 0; k < 4; ++k) {
            float h0 = sb1[lane], h1 = sb1[lane + 32];
#pragma unroll
            for (int q = 0; q < 8; ++q) {
                float e = em[k][q];
                h0 += e * sw1[q * 64 + lane];
                h1 += e * sw1[q * 64 + lane + 32];
            }
            hb[k * 64 + lane]      = silu_f(h0);
            hb[k * 64 + 32 + lane] = silu_f(h1);
        }
        float acc[5][4];
#pragma unroll
        for (int p = 0; p < 5; ++p)
#pragma unroll
            for (int k = 0; k < 4; ++k) acc[p][k] = 0.f;

#pragma unroll 4
        for (int j = 0; j < 64; ++j) {
            const float* wr = &sw2[j * 160 + lane];
            float w0 = wr[0], w1 = wr[32], w2 = wr[64], w3 = wr[96], w4 = wr[128];
#pragma unroll
            for (int k = 0; k < 4; ++k) {
                float hj = hb[k * 64 + j];
                acc[0][k] += hj * w0;
                acc[1][k] += hj * w1;
                acc[2][k] += hj * w2;
                acc[3][k] += hj * w3;
                acc[4][k] += hj * w4;
            }
        }
#pragma unroll
        for (int k = 0; k < 4; ++k) {
            if (k >= ne) break;
            int e = eid[k];
            int src = edge_src[e];
            float4 at = *(const float4*)&edge_attrs[(long)e * 4];
            float xs  = x_s[(long)src * 32 + lane];
            float xv0 = x_v[(long)src * 96 +      lane];
            float xv1 = x_v[(long)src * 96 + 32 + lane];
            float xv2 = x_v[(long)src * 96 + 64 + lane];
            float w00 = acc[0][k], w01 = acc[1][k], w10 = acc[2][k];
            float w11s = acc[3][k], w11v = acc[4][k];
            as0 += w00 * xs * at.x;
            float dot = xv0 * at.y + xv1 * at.z + xv2 * at.w;
            as1 += w11s * dot * INV_SQRT3;
            float t01 = w01 * xs;
            av[0] += t01 * at.y; av[1] += t01 * at.z; av[2] += t01 * at.w;
            float t10 = w10 * at.x;
            av[3] += t10 * xv0; av[4] += t10 * xv1; av[5] += t10 * xv2;
            float k2 = w11v * INV_SQRT2;
            av[6] += k2 * (xv1 * at.w - xv2 * at.z);
            av[7] += k2 * (xv2 * at.y - xv0 * at.w);
            av[8] += k2 * (xv0 * at.z - xv1 * at.y);
        }
    }

    asbuf[g][lane]      = as0 * INV_NEI;
    asbuf[g][32 + lane] = as1 * INV_NEI;
#pragma unroll
    for (int p = 0; p < 3; ++p)
#pragma unroll
        for (int c = 0; c < 3; ++c)
            avbuf[g][(p * 32 + lane) * 3 + c] = av[p * 3 + c] * INV_NEI;

    *(float4*)&hb[lane * 4] = *(const float4*)&node_feats[(long)n * 128 + lane * 4];
    if (lane < 16) hb[128 + lane] = node_attrs[(long)n * 16 + lane];

    int o = lane;
    float ys0 = 0.f, ys1 = 0.f, yv0 = 0.f, yv1 = 0.f, yv2 = 0.f;
#pragma unroll 8
    for (int u = 0; u < 64; ++u) {
        float as = asbuf[g][u];
        ys0 += as * W2_s[u * 64 + o];
        ys1 += as * W2_s[u * 64 + 32 + o];
    }
#pragma unroll 8
    for (int u = 0; u < 96; ++u) {
        float wv = W2_v[u * 32 + o];
        yv0 += avbuf[g][u * 3 + 0] * wv;
        yv1 += avbuf[g][u * 3 + 1] * wv;
        yv2 += avbuf[g][u * 3 + 2] * wv;
    }
    float att[16];
#pragma unroll
    for (int a = 0; a < 16; ++a) att[a] = hb[128 + a];
    for (int u = 0; u < 32; ++u) {
        const float* Wsp = &Wsc_s[u * 1024 + o];
        const float* Wvp = &Wsc_v[u * 512 + o];
        float t0 = 0.f, t1 = 0.f, tv = 0.f;
#pragma unroll
        for (int a = 0; a < 16; ++a) {
            float aa = att[a];
            t0 += aa * Wsp[a * 64];
            t1 += aa * Wsp[a * 64 + 32];
            tv += aa * Wvp[a * 32];
        }
        float su = hb[u];
        ys0 += su * t0;
        ys1 += su * t1;
        float vv0 = hb[32 + u * 3 + 0];
        float vv1 = hb[32 + u * 3 + 1];
        float vv2 = hb[32 + u * 3 + 2];
        yv0 += vv0 * tv;
        yv1 += vv1 * tv;
        yv2 += vv2 * tv;
    }
    float os   = silu_f(ys0);
    float gate = silu_f(ys1);
    long base = (long)n * 128;
    out[base + o] = hb[o] + os;
    out[base + 32 + o * 3 + 0] = hb[32 + o * 3 + 0] + yv0 * gate;
    out[base + 32 + o * 3 + 1] = hb[32 + o * 3 + 1] + yv1 * gate;
    out[base + 32 + o * 3 + 2] = hb[32 + o * 3 + 2] + yv2 * gate;
}

// ---------------------------------------------------------------------------
extern "C" void kernel_launch(void* const* d_in, const int* in_sizes, int n_in,
                              void* d_out, int out_size, void* d_ws, size_t ws_size,
                              hipStream_t stream) {
    const float* node_feats     = (const float*)d_in[0];
    const float* node_attrs     = (const float*)d_in[1];
    const float* edge_embedding = (const float*)d_in[2];
    const float* edge_attrs     = (const float*)d_in[3];
    const int*   edge_src       = (const int*)d_in[4];
    const int*   edge_dst       = (const int*)d_in[5];
    const float* W1_s  = (const float*)d_in[6];
    const float* W1_v  = (const float*)d_in[7];
    const float* fc_w1 = (const float*)d_in[8];
    const float* fc_b1 = (const float*)d_in[9];
    const float* fc_w2 = (const float*)d_in[10];
    const float* W2_s  = (const float*)d_in[11];
    const float* W2_v  = (const float*)d_in[12];
    const float* Wsc_s = (const float*)d_in[13];
    const float* Wsc_v = (const float*)d_in[14];
    float* out = (float*)d_out;

    float* ws  = (float*)d_ws;
    float* x_s = ws;                       // NN*32 floats
    float* x_v = ws + (long)NN * 32;       // NN*96 floats (planar)
    int* ibase    = (int*)(ws + (long)NN * 128);
    int* counts   = ibase;                 // NN
    int* row_ptr  = ibase + NN;            // NN+1
    int* cursor   = ibase + 2 * NN + 1;    // NN
    int* edge_ids = ibase + 3 * NN + 1;    // NE

    long intWords  = 3L * NN + 4 + NE;             // padded to 16B
    float* w2t  = (float*)(ibase + intWords);      // 10240 floats
    float* wbuf = w2t + 10240;                     // NE*160 floats (512 MB)
    size_t needWords = (size_t)NN * 128 + intWords + 10240 + (size_t)NE * 160;
    size_t need = needWords * sizeof(float);

    hipMemsetAsync(counts, 0, (size_t)NN * sizeof(int), stream);
    k_hist<<<(NE + 255) / 256, 256, 0, stream>>>(edge_dst, counts);
    k_node_transform<<<(NN + 7) / 8, 256, 0, stream>>>(node_feats, W1_s, W1_v, x_s, x_v);
    k_scan<<<1, 1024, 0, stream>>>(counts, row_ptr, cursor);
    k_fill<<<(NE + 255) / 256, 256, 0, stream>>>(edge_dst, cursor, edge_ids);

    if (ws_size >= need) {
        k_w2t<<<40, 256, 0, stream>>>(fc_w2, w2t);
        k_edge_mlp<<<NE / 256, 256, 0, stream>>>(edge_embedding, edge_ids,
                                                 fc_w1, fc_b1, w2t, wbuf);
        k_gather<<<(NN + 7) / 8, 256, 0, stream>>>(edge_attrs, edge_src, wbuf,
                                                   x_s, x_v, row_ptr, edge_ids,
                                                   node_feats, node_attrs,
                                                   W2_s, W2_v, Wsc_s, Wsc_v, out);
    } else {
        k_gather_fused<<<(NN + 7) / 8, 256, 0, stream>>>(edge_embedding, edge_attrs, edge_src,
                                                         fc_w1, fc_b1, fc_w2, x_s, x_v,
                                                         row_ptr, edge_ids,
                                                         node_feats, node_attrs,
                                                         W2_s, W2_v, Wsc_s, Wsc_v, out);
    }
}